// Round 5
// baseline (164.747 us; speedup 1.0000x reference)
//
#include <hip/hip_runtime.h>

// TorchPatchNN: unfold(7x7) -> NN argmin over 8100 keys (D=147) -> gather value -> fold mean.
// Round 10: break the register-wall occupancy cap. R9 analysis with correct per-SIMD units:
//  MFMA duty ~10%, LDS ~34%, L2 ~20%, Occupancy 20% (= 2 waves/SIMD, reg-capped at
//  116 VGPR + 128 AGPR on the unified file). Latency-bound => the lever is occupancy.
//  - Wave tile 64x64 -> 64x32 (block 128x64, grid 8192): acc 128 -> 64 AGPR. Bit-identical
//    numerics (same operand values, same MFMA order per output, same tie rule).
//  - __launch_bounds__(256,3): target <=170 regs/wave -> 3 blocks/CU = 12 waves/CU (+50% TLP).
//  - K-only LDS staging (8KB/chunk x2) + A-direct from global (L2-hot): R9's A-latency
//    exposure is exactly what the extra TLP hides; small LDS is what makes 3 blocks fit.
//  - XCD swizzle rectangle now 16qt x 64kt per XCD: Q 1.3MB + K 2.6MB = 3.9MB <= 4MiB L2.
//  Keep: setprio(1) compute-only, u64-packed branchless epilogue, unrolled k_fold.
//  SQ_LDS_BANK_CONFLICT pegs at 2^20 every round = saturated counter, not evidence.

#define NQ 8100
#define NK 8100
#define DD 147
#define HO 90
#define IMG 96
#define NCH 5                 // K chunks of 32 (160 padded K)
#define CST 262144            // f16 per chunk plane: 512 groups x 512
#define ARRN (NCH * CST)      // f16 per array

typedef _Float16 half8 __attribute__((ext_vector_type(8)));
typedef float f32x4 __attribute__((ext_vector_type(4)));

__device__ __forceinline__ void gld16(const _Float16* g, _Float16* l) {
    __builtin_amdgcn_global_load_lds(
        (const __attribute__((address_space(1))) unsigned int*)g,
        (__attribute__((address_space(3))) unsigned int*)l, 16, 0, 0);
}

// ---------------- prep: split Q/K into fp16 hi/lo (frag order) + key norms + init ---------
__global__ void k_prep(const float* __restrict__ query, const float* __restrict__ key,
                       _Float16* __restrict__ Qh, _Float16* __restrict__ Ql,
                       _Float16* __restrict__ Kh, _Float16* __restrict__ Kl,
                       float* __restrict__ kn, unsigned long long* __restrict__ fidx64) {
    const int bx = blockIdx.x;
    const bool isK = (blockIdx.y != 0);

    if (bx >= 640) {                      // fused k_kn region: 128 blocks on y==1
        if (!isK) return;
        int wave = threadIdx.x >> 6, lane = threadIdx.x & 63;
        int kb = ((bx - 640) * 4 + wave) * 16;
        for (int r = 0; r < 16; ++r) {
            int k = kb + r;
            float s = 0.f;
            if (k < NK)
                for (int d = lane; d < DD; d += 64) {
                    float v = key[k * DD + d];
                    s += v * v;
                }
#pragma unroll
            for (int off = 32; off; off >>= 1) s += __shfl_down(s, off, 64);
            if (lane == 0) {
                kn[k] = (k < NK) ? s : 1e30f;
                fidx64[k] = 0xFFFFFFFFFFFFFFFFull;   // ws re-poisoned every launch
            }
        }
        return;
    }

    int t = bx * 256 + threadIdx.x;             // 0 .. 163839 (ARRN/8)
    int c = t >> 15;                            // chunk
    int rem = t & 32767;                        // g*64 + lane
    int col = ((rem >> 6) << 4) + (rem & 15);   // g*16 + l15
    int quad = (rem >> 4) & 3;
    int kbase = c * 32 + quad * 8;

    float v[8];
#pragma unroll
    for (int j = 0; j < 8; ++j) {
        int k = kbase + j;
        float x = 0.f;
        if (k < DD && col < NQ) {
            if (isK) {
                x = key[col * DD + k];
            } else {
                int c3 = k / 49, r2 = k - 49 * c3;
                int rr = r2 / 7, ss = r2 - 7 * rr;
                int y = col / HO, xx = col - HO * y;
                x = query[(c3 * IMG + y + rr) * IMG + xx + ss];
            }
        }
        v[j] = x;
    }
    half8 h8, l8;
#pragma unroll
    for (int j = 0; j < 8; ++j) {
        _Float16 h = (_Float16)v[j];
        h8[j] = h;
        l8[j] = (_Float16)((v[j] - (float)h) * 2048.0f);
    }
    if (isK) {
        *(half8*)(Kh + t * 8) = h8;
        *(half8*)(Kl + t * 8) = l8;
    } else {
        *(half8*)(Qh + t * 8) = h8;
        *(half8*)(Ql + t * 8) = l8;
    }
}

// ---------------- main: split-f16 MFMA Q.K^T + fused argmin ----------------
// Block = 128 q-rows x 64 k-cols; wave tile 64x32; 3 blocks/CU target.
__launch_bounds__(256, 3)
__global__ void k_nn(const _Float16* __restrict__ Qh, const _Float16* __restrict__ Ql,
                     const _Float16* __restrict__ Kh, const _Float16* __restrict__ Kl,
                     const float* __restrict__ kn, unsigned long long* __restrict__ out) {
    __shared__ __align__(16) char smem[33792];   // K staging 2x8KB; epilogue [128][33] u64
    _Float16* sbase = (_Float16*)smem;

    const int tid = (int)threadIdx.x;
    const int wave = tid >> 6, lane = tid & 63;
    const int l15 = lane & 15, quad = lane >> 4;

    // XCD-aware swizzle: per XCD a 16qt x 64kt rectangle => Q 1.3MB + K 2.6MB L2-resident.
    const int b = (int)blockIdx.x;
    const int xcd = b & 7;
    const int i = b >> 3;                         // 0..1023 within XCD
    const int qt = (xcd >> 1) * 16 + (i & 15);    // 0..63  (128-row q tiles)
    const int kt = (xcd & 1) * 64 + (i >> 4);     // 0..127 (64-col k tiles)

    const int mbase = (wave >> 1) * 64;           // wave tile: 64x32 within 128x64
    const int nbase = (wave & 1) * 32;
    const int q0 = qt * 128, n0 = kt * 64;

    // K staging: 8 groups of 512 f16 per chunk (Kh g0-3, Kl g0-3); 2 gld16 per wave.
    const _Float16* gKsrc = (wave >= 2) ? Kl : Kh;
    const _Float16* gpK = gKsrc + (kt * 4 + (wave & 1) * 2) * 512 + lane * 8;
    _Float16* ldK = sbase + ((wave >= 2) ? 2048 : 0) + (wave & 1) * 1024 + lane * 8;

    // A-frag direct-load bases (frag-linear global layout, L2-hot)
    const int agrp = (mbase >> 4);                // (wave>>1)*4
    const int bgrp = (nbase >> 4);                // (wave&1)*2
    const _Float16* gAh = Qh + (qt * 8 + agrp) * 512 + lane * 8;
    const _Float16* gAl = Ql + (qt * 8 + agrp) * 512 + lane * 8;

    f32x4 acc0[4][2], acc1[4][2];                 // 64 AGPR total
#pragma unroll
    for (int ii = 0; ii < 4; ++ii)
#pragma unroll
        for (int j = 0; j < 2; ++j) {
            acc0[ii][j] = (f32x4)0.f;
            acc1[ii][j] = (f32x4)0.f;
        }

    // preamble: stage K chunk 0 into buffer 0
    gld16(gpK, ldK);
    gld16(gpK + 512, ldK + 512);

#pragma unroll
    for (int c = 0; c < NCH; ++c) {
        __syncthreads();   // drains vmcnt -> K buf[c&1] ready for all waves
        // A frags direct from global (L2-hot), issued first.
        half8 ah[4], al[4];
#pragma unroll
        for (int mt = 0; mt < 4; ++mt) {
            ah[mt] = *(const half8*)(gAh + c * CST + mt * 512);
            al[mt] = *(const half8*)(gAl + c * CST + mt * 512);
        }
        if (c + 1 < NCH) { // prefetch next K chunk into the other buffer
            const _Float16* gp = gpK + (c + 1) * CST;
            _Float16* ld = ldK + ((c + 1) & 1) * 4096;
            gld16(gp, ld);
            gld16(gp + 512, ld + 512);
        }

        const _Float16* sKh = sbase + (c & 1) * 4096;
        const _Float16* sKl = sKh + 2048;

        __builtin_amdgcn_s_setprio(1);
#pragma unroll
        for (int nt = 0; nt < 2; ++nt) {
            int boff = (bgrp + nt) * 512 + lane * 8;
            half8 bh = *(const half8*)(sKh + boff);
            half8 bl = *(const half8*)(sKl + boff);
#pragma unroll
            for (int mt = 0; mt < 4; ++mt) {
                acc0[mt][nt] = __builtin_amdgcn_mfma_f32_16x16x32_f16(ah[mt], bh, acc0[mt][nt], 0, 0, 0);
                acc1[mt][nt] = __builtin_amdgcn_mfma_f32_16x16x32_f16(ah[mt], bl, acc1[mt][nt], 0, 0, 0);
                acc1[mt][nt] = __builtin_amdgcn_mfma_f32_16x16x32_f16(al[mt], bh, acc1[mt][nt], 0, 0, 0);
            }
        }
        __builtin_amdgcn_s_setprio(0);
    }

    // epilogue: dist = kn - 2*(acc0 + acc1/2048); per-lane argmin over its 2 columns.
    // Pack (value,idx) into order-preserving u64: lexicographic u64-min == tie rule.
    float knv[2];
    int nglob[2];
#pragma unroll
    for (int nt = 0; nt < 2; ++nt) {
        nglob[nt] = n0 + nbase + nt * 16 + l15;
        knv[nt] = kn[nglob[nt]];
    }
    __syncthreads();   // done with staging LDS; reuse for reduction
    unsigned long long* redu = (unsigned long long*)smem;   // [128][33] u64 (33.8 KiB)

#pragma unroll
    for (int mt = 0; mt < 4; ++mt)
#pragma unroll
        for (int r = 0; r < 4; ++r) {
            float bv = 1e38f;
            int bn = 0x7fffffff;
#pragma unroll
            for (int nt = 0; nt < 2; ++nt) {   // ascending n within lane -> strict < ok
                float d = knv[nt] - 2.0f * (acc0[mt][nt][r] + acc1[mt][nt][r] * (1.0f / 2048.0f));
                if (d < bv) { bv = d; bn = nglob[nt]; }
            }
            int m = mbase + mt * 16 + quad * 4 + r;        // C layout: row = quad*4 + reg
            int cidx = (wave & 1) * 16 + l15;              // 0..31 (two col-halves per row)
            unsigned u = __float_as_uint(bv);
            u = (u & 0x80000000u) ? ~u : (u | 0x80000000u);   // order-preserving map
            redu[m * 33 + cidx] = ((unsigned long long)u << 32) | (unsigned)bn;
        }
    __syncthreads();

    {   // all 256 threads: 2 per row, 16 u64-min each, pair-combine via shfl
        int row = tid >> 1;
        int base = (tid & 1) * 16;
        unsigned long long best = 0xFFFFFFFFFFFFFFFFull;
        const unsigned long long* rp = redu + row * 33 + base;
#pragma unroll
        for (int t2 = 0; t2 < 16; ++t2) {
            unsigned long long v = rp[t2];
            best = (v < best) ? v : best;
        }
        unsigned long long other = __shfl_xor(best, 1, 64);
        best = (other < best) ? other : best;
        if (!(tid & 1)) atomicMin(&out[q0 + row], best);
    }
}

// ---------------- gather + fold (overlap-add mean) ----------------
// Fully unrolled predicated 7x7: phase 1 issues 49 independent u32 index loads, phase 2
// issues 49 value loads with full ILP.
__global__ void k_fold(const float* __restrict__ value,
                       const unsigned long long* __restrict__ fidx64,
                       float* __restrict__ out) {
    int t = blockIdx.x * 128 + threadIdx.x;   // 3*96*96 = 27648
    if (t >= 3 * IMG * IMG) return;
    int c = t / (IMG * IMG);
    int rem = t % (IMG * IMG);
    int Y = rem / IMG, X = rem % IMG;
    const float* vbase = value + c * 49;
    const unsigned* fidx32 = (const unsigned*)fidx64;   // low word = row index

    int rows[49];
    bool oks[49];
#pragma unroll
    for (int i = 0; i < 7; ++i)
#pragma unroll
        for (int j = 0; j < 7; ++j) {
            int yy = Y - i, xx = X - j;
            bool ok = ((unsigned)yy < (unsigned)HO) && ((unsigned)xx < (unsigned)HO);
            int p = ok ? (yy * HO + xx) : 0;
            rows[i * 7 + j] = (int)fidx32[2 * p];
            oks[i * 7 + j] = ok;
        }
    float s = 0.f, cnt = 0.f;
#pragma unroll
    for (int i = 0; i < 7; ++i)
#pragma unroll
        for (int j = 0; j < 7; ++j) {
            int k = i * 7 + j;
            float v = vbase[rows[k] * DD + k];   // always in-bounds (row 0 when masked)
            if (oks[k]) { s += v; cnt += 1.f; }
        }
    out[t] = s / cnt;
}

extern "C" void kernel_launch(void* const* d_in, const int* in_sizes, int n_in,
                              void* d_out, int out_size, void* d_ws, size_t ws_size,
                              hipStream_t stream) {
    const float* query = (const float*)d_in[0];
    const float* key   = (const float*)d_in[1];
    const float* value = (const float*)d_in[2];
    float* out = (float*)d_out;

    _Float16* Qh = (_Float16*)d_ws;           // ARRN f16 each
    _Float16* Ql = Qh + ARRN;
    _Float16* Kh = Ql + ARRN;
    _Float16* Kl = Kh + ARRN;
    float* kn = (float*)(Kl + ARRN);          // 8192 f32
    unsigned long long* fidx64 = (unsigned long long*)(kn + 8192);   // 8192 u64

    dim3 gp(768, 2);   // 640 split blocks + 128 fused-kn blocks (y==1)
    k_prep<<<gp, 256, 0, stream>>>(query, key, Qh, Ql, Kh, Kl, kn, fidx64);
    k_nn<<<8192, 256, 0, stream>>>(Qh, Ql, Kh, Kl, kn, fidx64);
    k_fold<<<216, 128, 0, stream>>>(value, fidx64, out);
}

// Round 6
// 146.357 us; speedup vs baseline: 1.1256x; 1.1256x over previous
//
#include <hip/hip_runtime.h>

// TorchPatchNN: unfold(7x7) -> NN argmin over 8100 keys (D=147) -> gather value -> fold mean.
// Round 11: consolidation. R10's occupancy play raised Occ 20->30% but REGRESSED k_nn
//  (84.6 vs R8's 72.1): doubling block count doubled per-phase fixed costs (barriers,
//  A-load total traffic) while halving per-phase MFMA work. R9's A-direct also regressed
//  (75.7). Conclusion: R8 structure is the empirical optimum for k_nn -> exact revert
//  (full LDS staging of Qh/Ql/Kh/Kl, 128x128 block, 2 blocks/CU, setprio, u64 epilogue).
//  New: k_fold was 1.7 waves/CU (27648 threads) -- TLP-starved scattered loads. Now 8 lanes
//  per pixel (s=i-slot, s=7 idle), 7 j-loads each, shfl_down(width=8) tree, analytic count,
//  864 blocks = 13.5 waves/CU (8x TLP).
//  Non-k_nn bucket is ~81-87us persistent; totals track k_nn deltas round-over-round.
//  SQ_LDS_BANK_CONFLICT pegs at 2^20 = saturated counter, not evidence.
// Numerics unchanged (fp16 h + 2^-11*l split, 3 MFMA passes, tie-aware packed-u64 atomicMin).

#define NQ 8100
#define NK 8100
#define DD 147
#define HO 90
#define IMG 96
#define NCH 5                 // K chunks of 32 (160 padded K)
#define CST 262144            // f16 per chunk plane: 512 groups x 512
#define ARRN (NCH * CST)      // f16 per array

typedef _Float16 half8 __attribute__((ext_vector_type(8)));
typedef float f32x4 __attribute__((ext_vector_type(4)));

__device__ __forceinline__ void gld16(const _Float16* g, _Float16* l) {
    __builtin_amdgcn_global_load_lds(
        (const __attribute__((address_space(1))) unsigned int*)g,
        (__attribute__((address_space(3))) unsigned int*)l, 16, 0, 0);
}

// ---------------- prep: split Q/K into fp16 hi/lo (frag order) + key norms + init ---------
__global__ void k_prep(const float* __restrict__ query, const float* __restrict__ key,
                       _Float16* __restrict__ Qh, _Float16* __restrict__ Ql,
                       _Float16* __restrict__ Kh, _Float16* __restrict__ Kl,
                       float* __restrict__ kn, unsigned long long* __restrict__ fidx64) {
    const int bx = blockIdx.x;
    const bool isK = (blockIdx.y != 0);

    if (bx >= 640) {                      // fused k_kn region: 128 blocks on y==1
        if (!isK) return;
        int wave = threadIdx.x >> 6, lane = threadIdx.x & 63;
        int kb = ((bx - 640) * 4 + wave) * 16;
        for (int r = 0; r < 16; ++r) {
            int k = kb + r;
            float s = 0.f;
            if (k < NK)
                for (int d = lane; d < DD; d += 64) {
                    float v = key[k * DD + d];
                    s += v * v;
                }
#pragma unroll
            for (int off = 32; off; off >>= 1) s += __shfl_down(s, off, 64);
            if (lane == 0) {
                kn[k] = (k < NK) ? s : 1e30f;
                fidx64[k] = 0xFFFFFFFFFFFFFFFFull;   // ws re-poisoned every launch
            }
        }
        return;
    }

    int t = bx * 256 + threadIdx.x;             // 0 .. 163839 (ARRN/8)
    int c = t >> 15;                            // chunk
    int rem = t & 32767;                        // g*64 + lane
    int col = ((rem >> 6) << 4) + (rem & 15);   // g*16 + l15
    int quad = (rem >> 4) & 3;
    int kbase = c * 32 + quad * 8;

    float v[8];
#pragma unroll
    for (int j = 0; j < 8; ++j) {
        int k = kbase + j;
        float x = 0.f;
        if (k < DD && col < NQ) {
            if (isK) {
                x = key[col * DD + k];
            } else {
                int c3 = k / 49, r2 = k - 49 * c3;
                int rr = r2 / 7, ss = r2 - 7 * rr;
                int y = col / HO, xx = col - HO * y;
                x = query[(c3 * IMG + y + rr) * IMG + xx + ss];
            }
        }
        v[j] = x;
    }
    half8 h8, l8;
#pragma unroll
    for (int j = 0; j < 8; ++j) {
        _Float16 h = (_Float16)v[j];
        h8[j] = h;
        l8[j] = (_Float16)((v[j] - (float)h) * 2048.0f);
    }
    if (isK) {
        *(half8*)(Kh + t * 8) = h8;
        *(half8*)(Kl + t * 8) = l8;
    } else {
        *(half8*)(Qh + t * 8) = h8;
        *(half8*)(Ql + t * 8) = l8;
    }
}

// ---------------- main: split-f16 MFMA Q.K^T + fused argmin (R8 structure) ----------------
__launch_bounds__(256, 2)
__global__ void k_nn(const _Float16* __restrict__ Qh, const _Float16* __restrict__ Ql,
                     const _Float16* __restrict__ Kh, const _Float16* __restrict__ Kl,
                     const float* __restrict__ kn, unsigned long long* __restrict__ out) {
    __shared__ __align__(16) char smem[65536];   // 2 x 32 KiB stage buffers (aliased epilogue)
    _Float16* sbase = (_Float16*)smem;

    const int tid = (int)threadIdx.x;
    const int wave = tid >> 6, lane = tid & 63;
    const int l15 = lane & 15, quad = lane >> 4;

    // XCD-aware swizzle: blockIdx%8 == XCD (round-robin heuristic). Each XCD gets a
    // 16qt x 32kt rectangle => Q 1.28 MB + K 2.56 MB = 3.84 MB <= 4 MiB L2.
    const int b = (int)blockIdx.x;
    const int xcd = b & 7;
    const int i = b >> 3;                         // 0..511 within XCD
    const int qt = (xcd >> 1) * 16 + (i & 15);
    const int kt = (xcd & 1) * 32 + (i >> 4);

    const int mbase = (wave >> 1) * 64;           // wave tile: 64x64 within 128x128
    const int nbase = (wave & 1) * 64;
    const int q0 = qt * 128, n0 = kt * 128;

    // per-wave staging source: wave 0->Qh,1->Ql,2->Kh,3->Kl
    const _Float16* gsrc = (wave == 0) ? Qh : (wave == 1) ? Ql : (wave == 2) ? Kh : Kl;
    const int gbase = ((wave < 2) ? qt : kt) * 8;
    const _Float16* gp0 = gsrc + gbase * 512 + lane * 8;
    _Float16* ldst0 = sbase + wave * 4096 + lane * 8;

    f32x4 acc0[4][4], acc1[4][4];
#pragma unroll
    for (int ii = 0; ii < 4; ++ii)
#pragma unroll
        for (int j = 0; j < 4; ++j) {
            acc0[ii][j] = (f32x4)0.f;
            acc1[ii][j] = (f32x4)0.f;
        }

    const int agrp = (mbase >> 4);
    const int bgrp = (nbase >> 4);

    // preamble: stage chunk 0 into buffer 0
#pragma unroll
    for (int grp = 0; grp < 8; ++grp)
        gld16(gp0 + grp * 512, ldst0 + grp * 512);

#pragma unroll
    for (int c = 0; c < NCH; ++c) {
        __syncthreads();   // drains vmcnt -> buf[c&1] ready for all waves
        if (c + 1 < NCH) { // prefetch next chunk into the other buffer (full compute cover)
            const _Float16* gp = gp0 + (c + 1) * CST;
            _Float16* ld = ldst0 + ((c + 1) & 1) * 16384;
#pragma unroll
            for (int grp = 0; grp < 8; ++grp)
                gld16(gp + grp * 512, ld + grp * 512);
        }

        const _Float16* sQh = sbase + (c & 1) * 16384;
        const _Float16* sQl = sQh + 4096;
        const _Float16* sKh = sQh + 8192;
        const _Float16* sKl = sQh + 12288;

        // Compiler-scheduled burst (R8 form): hoisted frag reads + fine lgkmcnt is already
        // near-optimal. setprio(1) = T5 only: prefer the MFMA-phase wave over the other
        // block's staging wave on the same SIMD.
        __builtin_amdgcn_s_setprio(1);
        half8 ah[4], al[4];
#pragma unroll
        for (int mt = 0; mt < 4; ++mt) {
            int aoff = (agrp + mt) * 512 + lane * 8;
            ah[mt] = *(const half8*)(sQh + aoff);
            al[mt] = *(const half8*)(sQl + aoff);
        }
#pragma unroll
        for (int nt = 0; nt < 4; ++nt) {
            int boff = (bgrp + nt) * 512 + lane * 8;
            half8 bh = *(const half8*)(sKh + boff);
            half8 bl = *(const half8*)(sKl + boff);
#pragma unroll
            for (int mt = 0; mt < 4; ++mt) {
                acc0[mt][nt] = __builtin_amdgcn_mfma_f32_16x16x32_f16(ah[mt], bh, acc0[mt][nt], 0, 0, 0);
                acc1[mt][nt] = __builtin_amdgcn_mfma_f32_16x16x32_f16(ah[mt], bl, acc1[mt][nt], 0, 0, 0);
                acc1[mt][nt] = __builtin_amdgcn_mfma_f32_16x16x32_f16(al[mt], bh, acc1[mt][nt], 0, 0, 0);
            }
        }
        __builtin_amdgcn_s_setprio(0);
    }

    // epilogue: dist = kn - 2*(acc0 + acc1/2048); per-lane argmin over its 4 columns.
    // Pack (value,idx) into order-preserving u64: lexicographic u64-min == tie rule.
    float knv[4];
    int nglob[4];
#pragma unroll
    for (int nt = 0; nt < 4; ++nt) {
        nglob[nt] = n0 + nbase + nt * 16 + l15;
        knv[nt] = kn[nglob[nt]];
    }
    __syncthreads();   // done with staging LDS; reuse for reduction
    unsigned long long* redu = (unsigned long long*)smem;   // [128][33] u64 (33.8 KiB)

#pragma unroll
    for (int mt = 0; mt < 4; ++mt)
#pragma unroll
        for (int r = 0; r < 4; ++r) {
            float bv = 1e38f;
            int bn = 0x7fffffff;
#pragma unroll
            for (int nt = 0; nt < 4; ++nt) {   // ascending n within lane -> strict < ok
                float d = knv[nt] - 2.0f * (acc0[mt][nt][r] + acc1[mt][nt][r] * (1.0f / 2048.0f));
                if (d < bv) { bv = d; bn = nglob[nt]; }
            }
            int m = mbase + mt * 16 + quad * 4 + r;        // C layout: row = quad*4 + reg
            int cidx = (nbase >> 2) + l15;                 // 0..31
            unsigned u = __float_as_uint(bv);
            u = (u & 0x80000000u) ? ~u : (u | 0x80000000u);   // order-preserving map
            redu[m * 33 + cidx] = ((unsigned long long)u << 32) | (unsigned)bn;
        }
    __syncthreads();

    {   // all 256 threads: 2 per row, 16 u64-min each, pair-combine via shfl
        int row = tid >> 1;
        int base = (tid & 1) * 16;
        unsigned long long best = 0xFFFFFFFFFFFFFFFFull;
        const unsigned long long* rp = redu + row * 33 + base;
#pragma unroll
        for (int t2 = 0; t2 < 16; ++t2) {
            unsigned long long v = rp[t2];
            best = (v < best) ? v : best;
        }
        unsigned long long other = __shfl_xor(best, 1, 64);
        best = (other < best) ? other : best;
        if (!(tid & 1)) atomicMin(&out[q0 + row], best);
    }
}

// ---------------- gather + fold (overlap-add mean) ----------------
// 8 lanes per output pixel: lane-slot s=0..6 handles patch-row i=s (7 j-loads, ILP 7),
// s=7 idle; shfl_down(width=8) tree reduces; s==0 divides by ANALYTIC count and stores.
// 864 blocks x 256 = 13.5 waves/CU (was 1.7 -- TLP-starved scattered loads).
__global__ void k_fold(const float* __restrict__ value,
                       const unsigned long long* __restrict__ fidx64,
                       float* __restrict__ out) {
    int t = blockIdx.x * 256 + threadIdx.x;   // 3*96*96*8 = 221184
    int pix = t >> 3, s = t & 7;
    if (pix >= 3 * IMG * IMG) return;
    int c = pix / (IMG * IMG);
    int rem = pix % (IMG * IMG);
    int Y = rem / IMG, X = rem % IMG;

    float partial = 0.f;
    int yy = Y - s;
    if (s < 7 && (unsigned)yy < (unsigned)HO) {
        const unsigned* fidx32 = (const unsigned*)fidx64;   // low word = row index
        const float* vbase = value + c * 49 + s * 7;
        int rows[7];
        bool oks[7];
#pragma unroll
        for (int j = 0; j < 7; ++j) {
            int xx = X - j;
            bool ok = (unsigned)xx < (unsigned)HO;
            int p = ok ? (yy * HO + xx) : 0;
            rows[j] = (int)fidx32[2 * p];
            oks[j] = ok;
        }
#pragma unroll
        for (int j = 0; j < 7; ++j) {
            float v = vbase[rows[j] * DD + j];   // always in-bounds (row 0 when masked)
            if (oks[j]) partial += v;
        }
    }
    partial += __shfl_down(partial, 4, 8);
    partial += __shfl_down(partial, 2, 8);
    partial += __shfl_down(partial, 1, 8);
    if (s == 0) {
        int i0 = max(0, Y - (HO - 1)), i1 = min(6, Y);
        int j0 = max(0, X - (HO - 1)), j1 = min(6, X);
        float cnt = (float)((i1 - i0 + 1) * (j1 - j0 + 1));
        out[pix] = partial / cnt;
    }
}

extern "C" void kernel_launch(void* const* d_in, const int* in_sizes, int n_in,
                              void* d_out, int out_size, void* d_ws, size_t ws_size,
                              hipStream_t stream) {
    const float* query = (const float*)d_in[0];
    const float* key   = (const float*)d_in[1];
    const float* value = (const float*)d_in[2];
    float* out = (float*)d_out;

    _Float16* Qh = (_Float16*)d_ws;           // ARRN f16 each
    _Float16* Ql = Qh + ARRN;
    _Float16* Kh = Ql + ARRN;
    _Float16* Kl = Kh + ARRN;
    float* kn = (float*)(Kl + ARRN);          // 8192 f32
    unsigned long long* fidx64 = (unsigned long long*)(kn + 8192);   // 8192 u64

    dim3 gp(768, 2);   // 640 split blocks + 128 fused-kn blocks (y==1)
    k_prep<<<gp, 256, 0, stream>>>(query, key, Qh, Ql, Kh, Kl, kn, fidx64);
    k_nn<<<4096, 256, 0, stream>>>(Qh, Ql, Kh, Kl, kn, fidx64);
    k_fold<<<864, 256, 0, stream>>>(value, fidx64, out);
}

// Round 7
// 144.218 us; speedup vs baseline: 1.1423x; 1.0148x over previous
//
#include <hip/hip_runtime.h>

// TorchPatchNN: unfold(7x7) -> NN argmin over 8100 keys (D=147) -> gather value -> fold mean.
// Round 12: remove the k_nn barrier-lockstep entirely. R5-R11 evidence: every structure with
//  per-chunk __syncthreads pays a serial {all-load | all-MFMA} phase chain (R9's A-direct
//  exposed L2 latency precisely because the barrier forces all waves to load simultaneously).
//  Fragments are frag-linear in global and L2-resident under the XCD swizzle (Q 1.28MB +
//  K 2.56MB <= 4MiB/XCD), so: NO LDS staging, NO K-loop barriers -- all 16 frags per chunk
//  loaded global->VGPR (coalesced 16B/lane, L2-hot). Per-SIMD per-wave MFMA block = 931 cyc
//  >> L2 latency ~300 cyc => the 2 waves/SIMD drift and cover each other's load windows.
//  Model floor: max(MFMA 1862, L2 ~950) cyc/chunk/CU ~= 33us; predict 48-60us at 50-70% eff.
//  Regs: 128 AGPR + 64 frag VGPR + addr ~= 210 < 256 => occupancy unchanged.
//  Keep: setprio around MFMA cluster, u64-packed epilogue (LDS only there), R11 k_fold,
//  k_prep unchanged. Numerics bit-identical to R8/R11 k_nn.
//  SQ_LDS_BANK_CONFLICT should finally unpeg from 2^20 (staging LDS gone).

#define NQ 8100
#define NK 8100
#define DD 147
#define HO 90
#define IMG 96
#define NCH 5                 // K chunks of 32 (160 padded K)
#define CST 262144            // f16 per chunk plane: 512 groups x 512
#define ARRN (NCH * CST)      // f16 per array

typedef _Float16 half8 __attribute__((ext_vector_type(8)));
typedef float f32x4 __attribute__((ext_vector_type(4)));

// ---------------- prep: split Q/K into fp16 hi/lo (frag order) + key norms + init ---------
__global__ void k_prep(const float* __restrict__ query, const float* __restrict__ key,
                       _Float16* __restrict__ Qh, _Float16* __restrict__ Ql,
                       _Float16* __restrict__ Kh, _Float16* __restrict__ Kl,
                       float* __restrict__ kn, unsigned long long* __restrict__ fidx64) {
    const int bx = blockIdx.x;
    const bool isK = (blockIdx.y != 0);

    if (bx >= 640) {                      // fused k_kn region: 128 blocks on y==1
        if (!isK) return;
        int wave = threadIdx.x >> 6, lane = threadIdx.x & 63;
        int kb = ((bx - 640) * 4 + wave) * 16;
        for (int r = 0; r < 16; ++r) {
            int k = kb + r;
            float s = 0.f;
            if (k < NK)
                for (int d = lane; d < DD; d += 64) {
                    float v = key[k * DD + d];
                    s += v * v;
                }
#pragma unroll
            for (int off = 32; off; off >>= 1) s += __shfl_down(s, off, 64);
            if (lane == 0) {
                kn[k] = (k < NK) ? s : 1e30f;
                fidx64[k] = 0xFFFFFFFFFFFFFFFFull;   // ws re-poisoned every launch
            }
        }
        return;
    }

    int t = bx * 256 + threadIdx.x;             // 0 .. 163839 (ARRN/8)
    int c = t >> 15;                            // chunk
    int rem = t & 32767;                        // g*64 + lane
    int col = ((rem >> 6) << 4) + (rem & 15);   // g*16 + l15
    int quad = (rem >> 4) & 3;
    int kbase = c * 32 + quad * 8;

    float v[8];
#pragma unroll
    for (int j = 0; j < 8; ++j) {
        int k = kbase + j;
        float x = 0.f;
        if (k < DD && col < NQ) {
            if (isK) {
                x = key[col * DD + k];
            } else {
                int c3 = k / 49, r2 = k - 49 * c3;
                int rr = r2 / 7, ss = r2 - 7 * rr;
                int y = col / HO, xx = col - HO * y;
                x = query[(c3 * IMG + y + rr) * IMG + xx + ss];
            }
        }
        v[j] = x;
    }
    half8 h8, l8;
#pragma unroll
    for (int j = 0; j < 8; ++j) {
        _Float16 h = (_Float16)v[j];
        h8[j] = h;
        l8[j] = (_Float16)((v[j] - (float)h) * 2048.0f);
    }
    if (isK) {
        *(half8*)(Kh + t * 8) = h8;
        *(half8*)(Kl + t * 8) = l8;
    } else {
        *(half8*)(Qh + t * 8) = h8;
        *(half8*)(Ql + t * 8) = l8;
    }
}

// ---------------- main: split-f16 MFMA Q.K^T + fused argmin, barrier-free K-loop ----------
__launch_bounds__(256, 2)
__global__ void k_nn(const _Float16* __restrict__ Qh, const _Float16* __restrict__ Ql,
                     const _Float16* __restrict__ Kh, const _Float16* __restrict__ Kl,
                     const float* __restrict__ kn, unsigned long long* __restrict__ out) {
    __shared__ __align__(16) char smem[33792];   // epilogue reduction only: [128][33] u64

    const int tid = (int)threadIdx.x;
    const int wave = tid >> 6, lane = tid & 63;
    const int l15 = lane & 15, quad = lane >> 4;

    // XCD-aware swizzle: blockIdx%8 == XCD (round-robin heuristic). Each XCD gets a
    // 16qt x 32kt rectangle => Q 1.28 MB + K 2.56 MB = 3.84 MB <= 4 MiB L2.
    const int b = (int)blockIdx.x;
    const int xcd = b & 7;
    const int i = b >> 3;                         // 0..511 within XCD
    const int qt = (xcd >> 1) * 16 + (i & 15);
    const int kt = (xcd & 1) * 32 + (i >> 4);

    const int mbase = (wave >> 1) * 64;           // wave tile: 64x64 within 128x128
    const int nbase = (wave & 1) * 64;
    const int q0 = qt * 128, n0 = kt * 128;

    // frag-linear global bases (all coalesced 16B/lane, L2-hot under the swizzle)
    const int agrp = (mbase >> 4);
    const int bgrp = (nbase >> 4);
    const _Float16* gQh = Qh + (qt * 8 + agrp) * 512 + lane * 8;
    const _Float16* gQl = Ql + (qt * 8 + agrp) * 512 + lane * 8;
    const _Float16* gKh = Kh + (kt * 8 + bgrp) * 512 + lane * 8;
    const _Float16* gKl = Kl + (kt * 8 + bgrp) * 512 + lane * 8;

    f32x4 acc0[4][4], acc1[4][4];
#pragma unroll
    for (int ii = 0; ii < 4; ++ii)
#pragma unroll
        for (int j = 0; j < 4; ++j) {
            acc0[ii][j] = (f32x4)0.f;
            acc1[ii][j] = (f32x4)0.f;
        }

#pragma unroll
    for (int c = 0; c < NCH; ++c) {
        // 16 independent coalesced loads; no barrier anywhere in the K-loop. The compiler
        // hoists next-chunk loads into the current MFMA block as far as regs allow; across
        // waves, un-synced drift lets one wave's MFMA block cover the other's load window.
        half8 ah[4], al[4], bh[4], bl[4];
#pragma unroll
        for (int mt = 0; mt < 4; ++mt) {
            ah[mt] = *(const half8*)(gQh + c * CST + mt * 512);
            al[mt] = *(const half8*)(gQl + c * CST + mt * 512);
        }
#pragma unroll
        for (int nt = 0; nt < 4; ++nt) {
            bh[nt] = *(const half8*)(gKh + c * CST + nt * 512);
            bl[nt] = *(const half8*)(gKl + c * CST + nt * 512);
        }

        __builtin_amdgcn_s_setprio(1);
#pragma unroll
        for (int nt = 0; nt < 4; ++nt) {
#pragma unroll
            for (int mt = 0; mt < 4; ++mt) {
                acc0[mt][nt] = __builtin_amdgcn_mfma_f32_16x16x32_f16(ah[mt], bh[nt], acc0[mt][nt], 0, 0, 0);
                acc1[mt][nt] = __builtin_amdgcn_mfma_f32_16x16x32_f16(ah[mt], bl[nt], acc1[mt][nt], 0, 0, 0);
                acc1[mt][nt] = __builtin_amdgcn_mfma_f32_16x16x32_f16(al[mt], bh[nt], acc1[mt][nt], 0, 0, 0);
            }
        }
        __builtin_amdgcn_s_setprio(0);
    }

    // epilogue: dist = kn - 2*(acc0 + acc1/2048); per-lane argmin over its 4 columns.
    // Pack (value,idx) into order-preserving u64: lexicographic u64-min == tie rule.
    float knv[4];
    int nglob[4];
#pragma unroll
    for (int nt = 0; nt < 4; ++nt) {
        nglob[nt] = n0 + nbase + nt * 16 + l15;
        knv[nt] = kn[nglob[nt]];
    }
    unsigned long long* redu = (unsigned long long*)smem;   // [128][33] u64 (33.8 KiB)

#pragma unroll
    for (int mt = 0; mt < 4; ++mt)
#pragma unroll
        for (int r = 0; r < 4; ++r) {
            float bv = 1e38f;
            int bn = 0x7fffffff;
#pragma unroll
            for (int nt = 0; nt < 4; ++nt) {   // ascending n within lane -> strict < ok
                float d = knv[nt] - 2.0f * (acc0[mt][nt][r] + acc1[mt][nt][r] * (1.0f / 2048.0f));
                if (d < bv) { bv = d; bn = nglob[nt]; }
            }
            int m = mbase + mt * 16 + quad * 4 + r;        // C layout: row = quad*4 + reg
            int cidx = (nbase >> 2) + l15;                 // 0..31
            unsigned u = __float_as_uint(bv);
            u = (u & 0x80000000u) ? ~u : (u | 0x80000000u);   // order-preserving map
            redu[m * 33 + cidx] = ((unsigned long long)u << 32) | (unsigned)bn;
        }
    __syncthreads();

    {   // all 256 threads: 2 per row, 16 u64-min each, pair-combine via shfl
        int row = tid >> 1;
        int base = (tid & 1) * 16;
        unsigned long long best = 0xFFFFFFFFFFFFFFFFull;
        const unsigned long long* rp = redu + row * 33 + base;
#pragma unroll
        for (int t2 = 0; t2 < 16; ++t2) {
            unsigned long long v = rp[t2];
            best = (v < best) ? v : best;
        }
        unsigned long long other = __shfl_xor(best, 1, 64);
        best = (other < best) ? other : best;
        if (!(tid & 1)) atomicMin(&out[q0 + row], best);
    }
}

// ---------------- gather + fold (overlap-add mean) ----------------
// 8 lanes per output pixel: lane-slot s=0..6 handles patch-row i=s (7 j-loads, ILP 7),
// s=7 idle; shfl_down(width=8) tree reduces; s==0 divides by ANALYTIC count and stores.
// 864 blocks x 256 = 13.5 waves/CU.
__global__ void k_fold(const float* __restrict__ value,
                       const unsigned long long* __restrict__ fidx64,
                       float* __restrict__ out) {
    int t = blockIdx.x * 256 + threadIdx.x;   // 3*96*96*8 = 221184
    int pix = t >> 3, s = t & 7;
    if (pix >= 3 * IMG * IMG) return;
    int c = pix / (IMG * IMG);
    int rem = pix % (IMG * IMG);
    int Y = rem / IMG, X = rem % IMG;

    float partial = 0.f;
    int yy = Y - s;
    if (s < 7 && (unsigned)yy < (unsigned)HO) {
        const unsigned* fidx32 = (const unsigned*)fidx64;   // low word = row index
        const float* vbase = value + c * 49 + s * 7;
        int rows[7];
        bool oks[7];
#pragma unroll
        for (int j = 0; j < 7; ++j) {
            int xx = X - j;
            bool ok = (unsigned)xx < (unsigned)HO;
            int p = ok ? (yy * HO + xx) : 0;
            rows[j] = (int)fidx32[2 * p];
            oks[j] = ok;
        }
#pragma unroll
        for (int j = 0; j < 7; ++j) {
            float v = vbase[rows[j] * DD + j];   // always in-bounds (row 0 when masked)
            if (oks[j]) partial += v;
        }
    }
    partial += __shfl_down(partial, 4, 8);
    partial += __shfl_down(partial, 2, 8);
    partial += __shfl_down(partial, 1, 8);
    if (s == 0) {
        int i0 = max(0, Y - (HO - 1)), i1 = min(6, Y);
        int j0 = max(0, X - (HO - 1)), j1 = min(6, X);
        float cnt = (float)((i1 - i0 + 1) * (j1 - j0 + 1));
        out[pix] = partial / cnt;
    }
}

extern "C" void kernel_launch(void* const* d_in, const int* in_sizes, int n_in,
                              void* d_out, int out_size, void* d_ws, size_t ws_size,
                              hipStream_t stream) {
    const float* query = (const float*)d_in[0];
    const float* key   = (const float*)d_in[1];
    const float* value = (const float*)d_in[2];
    float* out = (float*)d_out;

    _Float16* Qh = (_Float16*)d_ws;           // ARRN f16 each
    _Float16* Ql = Qh + ARRN;
    _Float16* Kh = Ql + ARRN;
    _Float16* Kl = Kh + ARRN;
    float* kn = (float*)(Kl + ARRN);          // 8192 f32
    unsigned long long* fidx64 = (unsigned long long*)(kn + 8192);   // 8192 u64

    dim3 gp(768, 2);   // 640 split blocks + 128 fused-kn blocks (y==1)
    k_prep<<<gp, 256, 0, stream>>>(query, key, Qh, Ql, Kh, Kl, kn, fidx64);
    k_nn<<<4096, 256, 0, stream>>>(Qh, Ql, Kh, Kl, kn, fidx64);
    k_fold<<<864, 256, 0, stream>>>(value, fidx64, out);
}